// Round 6
// baseline (1059.947 us; speedup 1.0000x reference)
//
#include <hip/hip_runtime.h>

#define HID 64
#define LL 16
#define NLAYERS 4
#define NN 50000
#define NE 200000
#define PRR 1600000
#define DDIM 100000        // PRR / LL
#define MGRPS 3125         // NN / 16
#define GE_BASE 800000     // ge rows appended to g after NN*16 rows
#define GROWS 800064
#define N2P_CNT PRR
#define E2P_CNT (PRR / 2)
#define POOL_CNT DDIM
#define TOTENT (N2P_CNT + E2P_CNT + POOL_CNT)   // 2.5M
#define NBINS (DDIM + NN)                        // 150000
#define GEMM_BLOCKS 196    // ceil(3125/16); block GEMM_BLOCKS does ge tail copy

typedef __attribute__((ext_vector_type(8))) short bf16x8;
typedef __attribute__((ext_vector_type(4))) float f32x4;

__device__ __forceinline__ unsigned short f2bf(float x) {
    unsigned u = __float_as_uint(x);
    unsigned r = (u + 0x7fffu + ((u >> 16) & 1u)) >> 16;
    return (unsigned short)r;
}
__device__ __forceinline__ float bf2f(unsigned short v) {
    return __uint_as_float((unsigned)v << 16);
}

// ======================= CSR build (once per call) ==========================
__global__ void k_zero_i(int* __restrict__ b, int n) {
    int t = blockIdx.x * blockDim.x + threadIdx.x;
    if (t < n) b[t] = 0;
}
__global__ void k_set_term(int* __restrict__ start_all) {
    start_all[NBINS] = TOTENT;
}

// unified histogram + rank for n2p, e2p, pool
__global__ void k_hist_all(const int* __restrict__ n2p_rows,
                           const int* __restrict__ e2p_rows,
                           const int* __restrict__ pool_rows,
                           int* __restrict__ cnt, int* __restrict__ rank_all) {
    int k = blockIdx.x * blockDim.x + threadIdx.x;
    if (k >= TOTENT) return;
    int bin;
    if (k < N2P_CNT) {
        bin = n2p_rows[k] >> 4;
    } else if (k < N2P_CNT + E2P_CNT) {
        bin = e2p_rows[k - N2P_CNT] >> 4;
    } else {
        bin = DDIM + pool_rows[k - N2P_CNT - E2P_CNT];
    }
    rank_all[k] = atomicAdd(&cnt[bin], 1);
}

__global__ void __launch_bounds__(256) k_scan_block(const int* __restrict__ cnt,
                                                    int* __restrict__ excl,
                                                    int* __restrict__ partial, int B) {
    __shared__ int lds[1024];
    int tid = threadIdx.x;
    int base = blockIdx.x * 1024;
    int self[4];
    #pragma unroll
    for (int r = 0; r < 4; ++r) {
        int i = r * 256 + tid;
        self[r] = (base + i < B) ? cnt[base + i] : 0;
        lds[i] = self[r];
    }
    __syncthreads();
    for (int off = 1; off < 1024; off <<= 1) {
        int v[4];
        #pragma unroll
        for (int r = 0; r < 4; ++r) {
            int i = r * 256 + tid;
            v[r] = (i >= off) ? lds[i - off] : 0;
        }
        __syncthreads();
        #pragma unroll
        for (int r = 0; r < 4; ++r) lds[r * 256 + tid] += v[r];
        __syncthreads();
    }
    #pragma unroll
    for (int r = 0; r < 4; ++r) {
        int i = r * 256 + tid;
        if (base + i < B) excl[base + i] = lds[i] - self[r];
    }
    if (tid == 0) partial[blockIdx.x] = lds[1023];
}

__global__ void k_scan_partial(int* __restrict__ partial, int nb) {
    if (threadIdx.x == 0) {
        int run = 0;
        for (int i = 0; i < nb; ++i) { int v = partial[i]; partial[i] = run; run += v; }
    }
}

__global__ void k_scan_add(int* __restrict__ excl, const int* __restrict__ partial, int B) {
    int i = blockIdx.x * blockDim.x + threadIdx.x;
    if (i < B) excl[i] += partial[i >> 10];
}

// unified fill: ent = (payload_row, val_bits), atomic-free via start+rank
__global__ void k_fill_all(const int* __restrict__ n2p_rows, const int* __restrict__ n2p_cols,
                           const float* __restrict__ n2p_vals,
                           const int* __restrict__ e2p_rows, const int* __restrict__ e2p_cols,
                           const float* __restrict__ e2p_vals,
                           const int* __restrict__ pool_rows, const int* __restrict__ pool_cols,
                           const float* __restrict__ pool_vals,
                           const int* __restrict__ edge_feat,
                           const int* __restrict__ start_all, const int* __restrict__ rank_all,
                           uint2* __restrict__ ent_all) {
    int k = blockIdx.x * blockDim.x + threadIdx.x;
    if (k >= TOTENT) return;
    int bin; unsigned pay; float val;
    if (k < N2P_CNT) {
        int r = n2p_rows[k];
        bin = r >> 4;
        pay = (unsigned)n2p_cols[k] * 16u + (unsigned)(r & 15);
        val = n2p_vals[k];
    } else if (k < N2P_CNT + E2P_CNT) {
        int kk = k - N2P_CNT;
        int r = e2p_rows[kk];
        bin = r >> 4;
        pay = (unsigned)GE_BASE + (unsigned)edge_feat[e2p_cols[kk]] * 16u + (unsigned)(r & 15);
        val = e2p_vals[kk];
    } else {
        int kk = k - N2P_CNT - E2P_CNT;
        bin = DDIM + pool_rows[kk];
        pay = (unsigned)pool_cols[kk];
        val = pool_vals[kk];
    }
    ent_all[start_all[bin] + rank_all[k]] = make_uint2(pay, __float_as_uint(val));
}

// ===================== upfront prep for ALL layers ==========================
#define WTB_SZ (LL * HID * HID)     // 65536
#define D1WT_SZ (128 * HID)         // 8192
#define GE_SZ (4 * LL * HID)        // 4096
#define PER_LAYER (WTB_SZ + D1WT_SZ + GE_SZ)   // 77824

__global__ void k_prep_all(const float* __restrict__ weights,
                           const float* __restrict__ bond_emb,
                           const float* __restrict__ deg1_w,
                           unsigned short* __restrict__ wtB_all,
                           float* __restrict__ d1wT_all,
                           float* __restrict__ ge_all) {
    int t = blockIdx.x * blockDim.x + threadIdx.x;
    if (t >= NLAYERS * PER_LAYER) return;
    int i = t / PER_LAYER;
    int u = t % PER_LAYER;
    const float* w_i = weights + (size_t)i * WTB_SZ;
    if (u < WTB_SZ) {
        int b = u & 63, N = u >> 6;
        int a = N >> 6, c = N & 63;
        wtB_all[(size_t)i * WTB_SZ + u] = f2bf(w_i[(b * HID + c) * LL + a]);
    } else if (u < WTB_SZ + D1WT_SZ) {
        int v = u - WTB_SZ;
        int c = v & 63, j = v >> 6;
        d1wT_all[i * D1WT_SZ + v] = deg1_w[(size_t)i * D1WT_SZ + c * 128 + j];
    } else {
        int v = u - WTB_SZ - D1WT_SZ;
        int c = v & 63, a = (v >> 6) & 15, ty = v >> 10;
        float s = 0.f;
        for (int b = 0; b < HID; ++b)
            s += bond_emb[i * 4 * HID + ty * HID + b] * w_i[(b * HID + c) * LL + a];
        ge_all[i * GE_SZ + v] = s;
    }
}

// ============================ per-layer kernels =============================
__global__ void k_init_h(const int* __restrict__ node_feat,
                         const float* __restrict__ atom_emb,
                         float* __restrict__ h) {
    int t = blockIdx.x * blockDim.x + threadIdx.x;
    if (t >= NN * HID) return;
    int n = t >> 6, c = t & 63;
    h[t] = atom_emb[node_feat[n] * HID + c];
}

// MFMA GEMM with 4-way M-group B-reuse; last block copies ge tail rows into g
__global__ void __launch_bounds__(256) k_gemm_g_mfma(
        const float* __restrict__ h,
        const unsigned short* __restrict__ wtB,
        const float* __restrict__ ge_i,
        unsigned short* __restrict__ g) {
    if (blockIdx.x == GEMM_BLOCKS) {
        for (int t = threadIdx.x; t < GE_SZ; t += 256)
            g[(size_t)(GE_BASE + (t >> 6)) * HID + (t & 63)] = f2bf(ge_i[t]);
        return;
    }
    int wave = threadIdx.x >> 6;
    int lane = threadIdx.x & 63;
    int mg4 = blockIdx.x * 4 + wave;
    if (mg4 * 4 >= MGRPS) return;
    int mrow = lane & 15;
    int kgrp = lane >> 4;

    bf16x8 A0[4], A1[4];
    bool valid[4];
    #pragma unroll
    for (int i = 0; i < 4; ++i) {
        int mgrp = mg4 * 4 + i;
        valid[i] = (mgrp < MGRPS);
        if (valid[i]) {
            const float* hrow = h + ((size_t)mgrp * 16 + mrow) * HID;
            float4 f0 = *(const float4*)(hrow + kgrp * 8);
            float4 f1 = *(const float4*)(hrow + kgrp * 8 + 4);
            float4 f2 = *(const float4*)(hrow + 32 + kgrp * 8);
            float4 f3 = *(const float4*)(hrow + 32 + kgrp * 8 + 4);
            bf16x8 a0, a1;
            a0[0] = (short)f2bf(f0.x); a0[1] = (short)f2bf(f0.y);
            a0[2] = (short)f2bf(f0.z); a0[3] = (short)f2bf(f0.w);
            a0[4] = (short)f2bf(f1.x); a0[5] = (short)f2bf(f1.y);
            a0[6] = (short)f2bf(f1.z); a0[7] = (short)f2bf(f1.w);
            a1[0] = (short)f2bf(f2.x); a1[1] = (short)f2bf(f2.y);
            a1[2] = (short)f2bf(f2.z); a1[3] = (short)f2bf(f2.w);
            a1[4] = (short)f2bf(f3.x); a1[5] = (short)f2bf(f3.y);
            a1[6] = (short)f2bf(f3.z); a1[7] = (short)f2bf(f3.w);
            A0[i] = a0; A1[i] = a1;
        } else {
            bf16x8 z;
            #pragma unroll
            for (int tt = 0; tt < 8; ++tt) z[tt] = 0;
            A0[i] = z; A1[i] = z;
        }
    }

    const unsigned short* bp = wtB + (size_t)mrow * HID + kgrp * 8;
    unsigned short* gp[4];
    #pragma unroll
    for (int i = 0; i < 4; ++i)
        gp[i] = g + (size_t)((mg4 * 4 + i) * 16 + kgrp * 4) * 1024 + mrow;

    for (int ntile = 0; ntile < 64; ++ntile) {
        bf16x8 b0 = *(const bf16x8*)(bp);
        bf16x8 b1 = *(const bf16x8*)(bp + 32);
        #pragma unroll
        for (int i = 0; i < 4; ++i) {
            if (!valid[i]) continue;
            f32x4 acc = {0.f, 0.f, 0.f, 0.f};
            acc = __builtin_amdgcn_mfma_f32_16x16x32_bf16(A0[i], b0, acc, 0, 0, 0);
            acc = __builtin_amdgcn_mfma_f32_16x16x32_bf16(A1[i], b1, acc, 0, 0, 0);
            #pragma unroll
            for (int r = 0; r < 4; ++r)
                gp[i][(size_t)r * 1024 + ntile * 16] = f2bf(acc[r]);
        }
        bp += 16 * HID;
    }
}

// ===== fused gather(n2p+e2p) + relu + pool + degree-gate: one wave per node =====
// lane owns channel pair (2*lp, 2*lp+1); wave halves process even/odd entries.
__global__ void __launch_bounds__(256) k_gather_pool_gate(
        const int* __restrict__ qstart,       // start_all[0..DDIM]
        const int* __restrict__ pstart,       // start_all + DDIM, [0..NN]
        const uint2* __restrict__ ent,        // unified entries
        const unsigned short* __restrict__ g,
        const float* __restrict__ bias_i, const float* __restrict__ degs,
        const float* __restrict__ d0w, const float* __restrict__ d0b,
        const float* __restrict__ d1wT, const float* __restrict__ d1b,
        float* __restrict__ h) {
    int wid = (blockIdx.x * 256 + threadIdx.x) >> 6;   // node
    if (wid >= NN) return;
    int lane = threadIdx.x & 63;
    int half = lane >> 5;
    int lp = lane & 31;
    float2 bias2 = *(const float2*)(bias_i + 2 * lp);
    float accx = 0.f, accy = 0.f;

    int pe = pstart[wid], pend = pstart[wid + 1];
    for (; pe < pend; ++pe) {
        uint2 p = ent[pe];
        int d = (int)p.x;
        float pval = __uint_as_float(p.y);
        float a0x = 0.f, a0y = 0.f, a1x = 0.f, a1y = 0.f;
        float a2x = 0.f, a2y = 0.f, a3x = 0.f, a3y = 0.f;
        int j = qstart[d], je = qstart[d + 1];
        for (; j + 7 < je; j += 8) {
            uint2 e0 = ent[j + half];
            uint2 e1 = ent[j + 2 + half];
            uint2 e2 = ent[j + 4 + half];
            uint2 e3 = ent[j + 6 + half];
            unsigned g0 = *(const unsigned*)(g + (size_t)e0.x * HID + 2 * lp);
            unsigned g1 = *(const unsigned*)(g + (size_t)e1.x * HID + 2 * lp);
            unsigned g2 = *(const unsigned*)(g + (size_t)e2.x * HID + 2 * lp);
            unsigned g3 = *(const unsigned*)(g + (size_t)e3.x * HID + 2 * lp);
            float v0 = __uint_as_float(e0.y), v1 = __uint_as_float(e1.y);
            float v2 = __uint_as_float(e2.y), v3 = __uint_as_float(e3.y);
            a0x += v0 * bf2f((unsigned short)(g0 & 0xffffu));
            a0y += v0 * bf2f((unsigned short)(g0 >> 16));
            a1x += v1 * bf2f((unsigned short)(g1 & 0xffffu));
            a1y += v1 * bf2f((unsigned short)(g1 >> 16));
            a2x += v2 * bf2f((unsigned short)(g2 & 0xffffu));
            a2y += v2 * bf2f((unsigned short)(g2 >> 16));
            a3x += v3 * bf2f((unsigned short)(g3 & 0xffffu));
            a3y += v3 * bf2f((unsigned short)(g3 >> 16));
        }
        for (; j < je; j += 2) {
            if (j + half < je) {
                uint2 e0 = ent[j + half];
                unsigned g0 = *(const unsigned*)(g + (size_t)e0.x * HID + 2 * lp);
                float v0 = __uint_as_float(e0.y);
                a1x += v0 * bf2f((unsigned short)(g0 & 0xffffu));
                a1y += v0 * bf2f((unsigned short)(g0 >> 16));
            }
        }
        float qx = (a0x + a1x) + (a2x + a3x);
        float qy = (a0y + a1y) + (a2y + a3y);
        qx += __shfl(qx, lane ^ 32, 64);
        qy += __shfl(qy, lane ^ 32, 64);
        accx += pval * fmaxf(qx + bias2.x, 0.f);
        accy += pval * fmaxf(qy + bias2.y, 0.f);
    }

    // degree gate (halves split the 64 broadcast steps)
    float deg = degs[wid];
    float rv0 = fmaxf(deg * d0w[lane] + d0b[lane], 0.f);
    float rv1 = fmaxf(deg * d0w[64 + lane] + d0b[64 + lane], 0.f);
    float gfx = 0.f, gfy = 0.f;
    #pragma unroll 8
    for (int t = 0; t < 32; ++t) {
        int j2 = half * 32 + t;
        float f0 = __shfl(rv0, j2, 64);
        float f1 = __shfl(rv1, j2, 64);
        float2 w0 = *(const float2*)(d1wT + j2 * HID + 2 * lp);
        float2 w1 = *(const float2*)(d1wT + (64 + j2) * HID + 2 * lp);
        gfx += w0.x * f0 + w1.x * f1;
        gfy += w0.y * f0 + w1.y * f1;
    }
    gfx += __shfl(gfx, lane ^ 32, 64);
    gfy += __shfl(gfy, lane ^ 32, 64);
    float2 d1b2 = *(const float2*)(d1b + 2 * lp);
    gfx += d1b2.x; gfy += d1b2.y;
    if (half == 0) {
        float2 res = { accx * gfx, accy * gfy };
        *(float2*)(h + (size_t)wid * HID + 2 * lp) = res;
    }
}

// ============================== epilogue ====================================
__global__ void k_reduce(const float* __restrict__ h, float* __restrict__ partial_red) {
    __shared__ float lds[256];
    int tid = threadIdx.x;
    float s = 0.f;
    for (int idx = blockIdx.x * 256 + tid; idx < NN * HID; idx += gridDim.x * 256)
        s += h[idx];
    lds[tid] = s;
    __syncthreads();
    if (tid < 64)
        partial_red[blockIdx.x * 64 + tid] = lds[tid] + lds[tid + 64] + lds[tid + 128] + lds[tid + 192];
}

__global__ void k_final(const float* __restrict__ partial_red,
                        const float* __restrict__ fw,
                        const float* __restrict__ fb, float* __restrict__ out) {
    int lane = threadIdx.x;   // 64 threads
    float s = 0.f;
    for (int b = 0; b < 256; ++b) s += partial_red[b * 64 + lane];
    float v = s * (1.0f / NN) * fw[lane];
    for (int off = 32; off; off >>= 1) v += __shfl_down(v, off, 64);
    if (lane == 0) out[0] = v + fb[0];
}

// ============================================================================
extern "C" void kernel_launch(void* const* d_in, const int* in_sizes, int n_in,
                              void* d_out, int out_size, void* d_ws, size_t ws_size,
                              hipStream_t stream) {
    const int*   node_feat = (const int*)d_in[0];
    const int*   edge_feat = (const int*)d_in[1];
    const float* degs      = (const float*)d_in[2];
    const int*   n2p_rows  = (const int*)d_in[3];
    const int*   n2p_cols  = (const int*)d_in[4];
    const float* n2p_vals  = (const float*)d_in[5];
    const int*   e2p_rows  = (const int*)d_in[6];
    const int*   e2p_cols  = (const int*)d_in[7];
    const float* e2p_vals  = (const float*)d_in[8];
    const int*   pool_rows = (const int*)d_in[9];
    const int*   pool_cols = (const int*)d_in[10];
    const float* pool_vals = (const float*)d_in[11];
    const float* atom_emb  = (const float*)d_in[13];
    const float* bond_emb  = (const float*)d_in[14];
    const float* weights   = (const float*)d_in[15];
    const float* bias      = (const float*)d_in[16];
    const float* deg0_w    = (const float*)d_in[17];
    const float* deg0_b    = (const float*)d_in[18];
    const float* deg1_w    = (const float*)d_in[19];
    const float* deg1_b    = (const float*)d_in[20];
    const float* final_w   = (const float*)d_in[21];
    const float* final_b   = (const float*)d_in[22];
    float* out = (float*)d_out;

    char* wsb = (char*)d_ws;
    size_t off = 0;
    auto alloc = [&](size_t bytes) -> void* {
        void* ptr = wsb + off;
        off += (bytes + 255) & ~(size_t)255;
        return ptr;
    };
    float*          h        = (float*)alloc((size_t)NN * HID * 4);               // 12.8 MB
    unsigned short* g        = (unsigned short*)alloc((size_t)GROWS * HID * 2);   // 102.4 MB
    unsigned short* wtB_all  = (unsigned short*)alloc((size_t)NLAYERS * WTB_SZ * 2); // 0.5 MB
    float*          d1wT_all = (float*)alloc((size_t)NLAYERS * D1WT_SZ * 4);
    float*          ge_all   = (float*)alloc((size_t)NLAYERS * GE_SZ * 4);
    float*          partial_red = (float*)alloc(256 * 64 * 4);
    int*   start_all = (int*)alloc((size_t)(NBINS + 1) * 4);
    int*   cnt       = (int*)alloc((size_t)NBINS * 4);
    int*   partial   = (int*)alloc(512 * 4);
    int*   rank_all  = (int*)alloc((size_t)TOTENT * 4);       // 10 MB
    uint2* ent_all   = (uint2*)alloc((size_t)TOTENT * 8);     // 20 MB

    // ---------------- CSR build (shared across layers) ----------------------
    k_zero_i<<<(NBINS + 255) / 256, 256, 0, stream>>>(cnt, NBINS);
    k_hist_all<<<(TOTENT + 255) / 256, 256, 0, stream>>>(n2p_rows, e2p_rows, pool_rows,
                                                         cnt, rank_all);
    k_scan_block<<<(NBINS + 1023) / 1024, 256, 0, stream>>>(cnt, start_all, partial, NBINS);
    k_scan_partial<<<1, 64, 0, stream>>>(partial, (NBINS + 1023) / 1024);
    k_scan_add<<<(NBINS + 255) / 256, 256, 0, stream>>>(start_all, partial, NBINS);
    k_set_term<<<1, 1, 0, stream>>>(start_all);
    k_fill_all<<<(TOTENT + 255) / 256, 256, 0, stream>>>(n2p_rows, n2p_cols, n2p_vals,
                                                         e2p_rows, e2p_cols, e2p_vals,
                                                         pool_rows, pool_cols, pool_vals,
                                                         edge_feat, start_all, rank_all, ent_all);

    // ---------------- prep for all layers -----------------------------------
    k_prep_all<<<(NLAYERS * PER_LAYER + 255) / 256, 256, 0, stream>>>(
        weights, bond_emb, deg1_w, wtB_all, d1wT_all, ge_all);

    // ---------------- layers ------------------------------------------------
    k_init_h<<<(NN * HID + 255) / 256, 256, 0, stream>>>(node_feat, atom_emb, h);

    for (int i = 0; i < NLAYERS; ++i) {
        k_gemm_g_mfma<<<GEMM_BLOCKS + 1, 256, 0, stream>>>(
            h, wtB_all + (size_t)i * WTB_SZ, ge_all + (size_t)i * GE_SZ, g);
        k_gather_pool_gate<<<(NN + 3) / 4, 256, 0, stream>>>(
            start_all, start_all + DDIM, ent_all, g,
            bias + i * HID, degs,
            deg0_w + i * 2 * HID, deg0_b + i * 2 * HID,
            d1wT_all + (size_t)i * D1WT_SZ, deg1_b + i * HID, h);
    }

    k_reduce<<<256, 256, 0, stream>>>(h, partial_red);
    k_final<<<1, 64, 0, stream>>>(partial_red, final_w, final_b, out);
}